// Round 2
// 1013.622 us; speedup vs baseline: 1.0124x; 1.0124x over previous
//
#include <hip/hip_runtime.h>
#include <math.h>

#define V 64
#define T 8192
#define DA 256
#define DS 256
#define KR 8
#define KA 40
#define KRDU 512

// ---- output layout (floats, concatenated in reference return order) ----
#define OUT_PDET   0
#define OUT_TAU    1
#define OUT_YHAT   2
#define OUT_E      42
#define OUT_EVIEW  524330
#define OUT_RVIEW  524394
#define OUT_IVIEW  524458
#define OUT_STARTS 524522
#define OUT_ENDS   1048810
#define OUT_FLAG   1573098

// ---- workspace layout ----
#define WS_W    0      // float[256]: w = Wwin^T zsn (atomic-accumulated)
#define WS_ESUM 256    // float[64]: per-view sum of e
#define WS_ZSN  320    // float[256]: normalized zs
#define WS_CNT  576    // int: worklist counter
#define WS_LIST 640    // int[CAP]: flagged row indices

#define CAP    65536
#define MARGIN 4e-3f
#define HROWB  264     // bf16 row stride in LDS (528 B)

typedef __attribute__((ext_vector_type(8))) short short8;
typedef __attribute__((ext_vector_type(4))) float f32x4;

__device__ __forceinline__ unsigned pack_bf16(float a, float b) {
    union { float f; unsigned u; } x, y; x.f = a; y.f = b;
    unsigned ua = (x.u + 0x7FFFu + ((x.u >> 16) & 1u)) >> 16;
    unsigned ub = (y.u + 0x7FFFu + ((y.u >> 16) & 1u)) & 0xFFFF0000u;
    return ua | ub;
}

// ============================ kernel A: small heads ============================
__global__ __launch_bounds__(256) void head_kernel(
    const float* __restrict__ alpha, const float* __restrict__ pi,
    const float* __restrict__ US, const float* __restrict__ Ws_w,
    const float* __restrict__ Ws_b, const float* __restrict__ det_w,
    const float* __restrict__ det_b, const float* __restrict__ cls_w,
    const float* __restrict__ cls_b,
    const float* __restrict__ tau_c0, const float* __restrict__ lamU,
    const float* __restrict__ lamC, const float* __restrict__ lamP,
    const float* __restrict__ lamPi, const float* __restrict__ nu,
    const float* __restrict__ risk,
    float* __restrict__ out, float* __restrict__ ws, int* __restrict__ wsi)
{
    __shared__ float us[KRDU];
    __shared__ float zs[DS];
    __shared__ float red[256];
    const int tid = threadIdx.x;
    const int rr = tid >> 4;
    const int c  = tid & 15;

    us[tid]       = US[tid];
    us[tid + 256] = US[tid + 256];
    __syncthreads();

    // zs = US @ Ws_w^T (coalesced)
    for (int rg = 0; rg < 16; ++rg) {
        int row = rg * 16 + rr;
        const float4* wr = (const float4*)(Ws_w + (size_t)row * KRDU);
        float a = 0.0f;
        #pragma unroll
        for (int jj = 0; jj < 8; ++jj) {
            float4 w4 = wr[jj * 16 + c];
            int j0 = (jj * 16 + c) * 4;
            a += w4.x * us[j0] + w4.y * us[j0+1] + w4.z * us[j0+2] + w4.w * us[j0+3];
        }
        #pragma unroll
        for (int m = 8; m >= 1; m >>= 1) a += __shfl_xor(a, m);
        if (c == 0) zs[row] = a;
    }
    __syncthreads();
    float zv = zs[tid] + Ws_b[tid];
    __syncthreads();
    zs[tid] = zv;

    // s = zs . det_w + det_b
    red[tid] = zv * det_w[tid];
    __syncthreads();
    for (int off = 128; off > 0; off >>= 1) { if (tid < off) red[tid] += red[tid+off]; __syncthreads(); }
    float s_det = red[0] + det_b[0];
    __syncthreads();

    // ||zs||
    red[tid] = zv * zv;
    __syncthreads();
    for (int off = 128; off > 0; off >>= 1) { if (tid < off) red[tid] += red[tid+off]; __syncthreads(); }
    float inv_n = 1.0f / fmaxf(sqrtf(red[0]), 1e-12f);
    __syncthreads();
    ws[WS_ZSN + tid] = zv * inv_n;

    // entropy(alpha)
    float term = 0.0f;
    if (tid < V) { float a = alpha[tid]; term = -a * logf(a + 1e-8f); }
    red[tid] = term;
    __syncthreads();
    for (int off = 128; off > 0; off >>= 1) { if (tid < off) red[tid] += red[tid+off]; __syncthreads(); }
    float C_alpha = 1.0f - red[0] / logf((float)V);
    __syncthreads();

    // entropy(pi)
    term = 0.0f;
    if (tid < KR) { float p = pi[tid]; term = -p * logf(p + 1e-8f); }
    red[tid] = term;
    __syncthreads();
    for (int off = 128; off > 0; off >>= 1) { if (tid < off) red[tid] += red[tid+off]; __syncthreads(); }
    float u_pi = red[0] / logf((float)KR);
    __syncthreads();

    float tau = tau_c0[0] - lamU[0]*nu[0] - lamC[0]*C_alpha + lamP[0]*risk[0] + lamPi[0]*u_pi;
    if (tid == 0) {
        out[OUT_TAU]  = tau;
        out[OUT_PDET] = 1.0f / (1.0f + expf(-(s_det - tau)));
        wsi[WS_CNT]   = 0;
    }

    // y_hat
    for (int rg = 0; rg < 3; ++rg) {
        int row = rg * 16 + rr;
        float a = 0.0f;
        if (row < KA) {
            const float4* cr4 = (const float4*)(cls_w + (size_t)row * DS);
            #pragma unroll
            for (int jj = 0; jj < 4; ++jj) {
                float4 w4 = cr4[jj * 16 + c];
                int j0 = (jj * 16 + c) * 4;
                a += w4.x * zs[j0] + w4.y * zs[j0+1] + w4.z * zs[j0+2] + w4.w * zs[j0+3];
            }
        }
        #pragma unroll
        for (int m = 8; m >= 1; m >>= 1) a += __shfl_xor(a, m);
        if (c == 0 && row < KA) out[OUT_YHAT + row] = 1.0f / (1.0f + expf(-(a + cls_b[row])));
    }

    ws[WS_W + tid] = 0.0f;
    if (tid < V) {
        out[OUT_RVIEW + tid] = -0.5f * alpha[tid];
        ws[WS_ESUM + tid] = 0.0f;
    }
}

// ============================ kernel A2: w = Wwin^T zsn ============================
__global__ __launch_bounds__(256) void wvec_kernel(const float* __restrict__ Wwin,
                                                   float* __restrict__ ws)
{
    __shared__ float zl[16];
    const int b = blockIdx.x;
    const int tid = threadIdx.x;
    if (tid < 16) zl[tid] = ws[WS_ZSN + b * 16 + tid];
    __syncthreads();
    float a = 0.0f;
    #pragma unroll
    for (int s = 0; s < 16; ++s) a += Wwin[(size_t)(b * 16 + s) * DA + tid] * zl[s];
    atomicAdd(&ws[WS_W + tid], a);
}

// ============================ kernel B: e scores ============================
// 512 blocks x 256 threads; block = 1024 rows of one view, 64 tiles of 16 rows.
// Wave w: B-frags for s in [w*64,(w+1)*64). num computed from MFMA z via zsn.
// Per-wave PRIVATE partial arrays in LDS -> one barrier per tile (staging) only.
// 2-tile-deep register prefetch (fA/fB), tile loop unrolled x2 (static indexing).
__global__ __launch_bounds__(256, 2) void escore_kernel(
    const float* __restrict__ h, const float* __restrict__ Wwin,
    const float* __restrict__ alpha,
    float* __restrict__ ws, int* __restrict__ wsi, float* __restrict__ out)
{
    __shared__ unsigned short hsb[2][16 * HROWB];   // 16896 B
    __shared__ float part_n[4][1024];               // 16 KB
    __shared__ float part_u[4][1024];               // 16 KB
    __shared__ float red[4];

    const int tid  = threadIdx.x;
    const int lane = tid & 63;
    const int wv   = tid >> 6;
    const int ln15 = lane & 15;
    const int lq   = lane >> 4;

    // ---- prologue: W fragments (fp32 -> bf16), s = wv*64 + st*16 + ln15 ----
    short8 Wf[4][8];
    {
        const int nbase = wv * 64 + ln15;
        #pragma unroll
        for (int st = 0; st < 4; ++st) {
            const float* wrow = Wwin + (size_t)(nbase + st * 16) * DA + lq * 8;
            #pragma unroll
            for (int kk = 0; kk < 8; ++kk) {
                float4 f0 = *(const float4*)(wrow + kk * 32);
                float4 f1 = *(const float4*)(wrow + kk * 32 + 4);
                union { short8 s; unsigned u[4]; } pk;
                pk.u[0] = pack_bf16(f0.x, f0.y);
                pk.u[1] = pack_bf16(f0.z, f0.w);
                pk.u[2] = pack_bf16(f1.x, f1.y);
                pk.u[3] = pack_bf16(f1.z, f1.w);
                Wf[st][kk] = pk.s;
            }
        }
    }
    float zl[4];
    #pragma unroll
    for (int st = 0; st < 4; ++st) zl[st] = ws[WS_ZSN + wv * 64 + st * 16 + ln15];

    const int view = blockIdx.x >> 3;
    const float rv = -0.5f * alpha[view];
    const long rowbase0 = (long)blockIdx.x * 1024;
    const float4* hg = (const float4*)(h + rowbase0 * DA);

    // preload tiles 0 and 1 (row = wv+4i within tile, col4 = lane)
    float4 fA[4], fB[4];
    #pragma unroll
    for (int i = 0; i < 4; ++i) fA[i] = hg[tid + 256 * i];
    #pragma unroll
    for (int i = 0; i < 4; ++i) fB[i] = hg[1024 + tid + 256 * i];

#define STAGE(FREG, P)                                                          \
    _Pragma("unroll")                                                           \
    for (int i = 0; i < 4; ++i) {                                               \
        unsigned u0 = pack_bf16(FREG[i].x, FREG[i].y);                          \
        unsigned u1 = pack_bf16(FREG[i].z, FREG[i].w);                          \
        *(uint2*)&hsb[P][(wv + 4 * i) * HROWB + lane * 4] = make_uint2(u0, u1); \
    }

#define LOADNEXT(FREG, TNEXT)                                                   \
    if ((TNEXT) < 64) {                                                         \
        const float4* ng = hg + (long)(TNEXT) * 1024;                           \
        _Pragma("unroll")                                                       \
        for (int i = 0; i < 4; ++i) FREG[i] = ng[tid + 256 * i];                \
    }

#define COMPUTE(P, TILE) {                                                              \
    f32x4 acc0 = (f32x4){0.f,0.f,0.f,0.f}, acc1 = (f32x4){0.f,0.f,0.f,0.f};             \
    f32x4 acc2 = (f32x4){0.f,0.f,0.f,0.f}, acc3 = (f32x4){0.f,0.f,0.f,0.f};             \
    _Pragma("unroll")                                                                   \
    for (int kk = 0; kk < 8; ++kk) {                                                    \
        short8 af = *(const short8*)&hsb[P][ln15 * HROWB + kk * 32 + lq * 8];           \
        acc0 = __builtin_amdgcn_mfma_f32_16x16x32_bf16(af, Wf[0][kk], acc0, 0, 0, 0);   \
        acc1 = __builtin_amdgcn_mfma_f32_16x16x32_bf16(af, Wf[1][kk], acc1, 0, 0, 0);   \
        acc2 = __builtin_amdgcn_mfma_f32_16x16x32_bf16(af, Wf[2][kk], acc2, 0, 0, 0);   \
        acc3 = __builtin_amdgcn_mfma_f32_16x16x32_bf16(af, Wf[3][kk], acc3, 0, 0, 0);   \
    }                                                                                   \
    float nr[4], nu_[4];                                                                \
    _Pragma("unroll")                                                                   \
    for (int reg = 0; reg < 4; ++reg) {                                                 \
        nr[reg]  = acc0[reg]*acc0[reg] + acc1[reg]*acc1[reg]                            \
                 + acc2[reg]*acc2[reg] + acc3[reg]*acc3[reg];                           \
        nu_[reg] = acc0[reg]*zl[0] + acc1[reg]*zl[1]                                    \
                 + acc2[reg]*zl[2] + acc3[reg]*zl[3];                                   \
    }                                                                                   \
    _Pragma("unroll")                                                                   \
    for (int m = 1; m <= 8; m <<= 1) {                                                  \
        _Pragma("unroll")                                                               \
        for (int reg = 0; reg < 4; ++reg) {                                             \
            nr[reg]  += __shfl_xor(nr[reg], m);                                         \
            nu_[reg] += __shfl_xor(nu_[reg], m);                                        \
        }                                                                               \
    }                                                                                   \
    if (ln15 == 0) {                                                                    \
        *(float4*)&part_n[wv][(TILE) * 16 + lq * 4] = make_float4(nr[0], nr[1], nr[2], nr[3]);      \
        *(float4*)&part_u[wv][(TILE) * 16 + lq * 4] = make_float4(nu_[0], nu_[1], nu_[2], nu_[3]);  \
    }                                                                                   \
}

    for (int it = 0; it < 32; ++it) {
        const int t0 = it * 2;
        // ---- half-step A: tile t0 in buffer 0 ----
        STAGE(fA, 0)
        LOADNEXT(fA, t0 + 2)       // issue before barrier; consumed 2 half-steps later
        __syncthreads();
        COMPUTE(0, t0)
        // ---- half-step B: tile t0+1 in buffer 1 ----
        STAGE(fB, 1)
        LOADNEXT(fB, t0 + 3)
        __syncthreads();
        COMPUTE(1, t0 + 1)
        // no barrier at loop end: part arrays are wave-private; hsb[0] write at
        // next iteration is separated from this COMPUTE(0) read by one barrier
    }

#undef STAGE
#undef LOADNEXT
#undef COMPUTE

    __syncthreads();

    // finalize: 1024 rows, 4 per thread
    float esum = 0.0f;
    #pragma unroll
    for (int j = 0; j < 4; ++j) {
        int r = j * 256 + tid;
        float nn = part_n[0][r] + part_n[1][r] + part_n[2][r] + part_n[3][r];
        float uu = part_u[0][r] + part_u[1][r] + part_u[2][r] + part_u[3][r];
        float e = uu / fmaxf(sqrtf(nn), 1e-12f);
        out[OUT_E + rowbase0 + r] = e;
        esum += e;
        if (fabsf(e - rv) < MARGIN) {
            int idx = atomicAdd(&wsi[WS_CNT], 1);
            if (idx < CAP) wsi[WS_LIST + idx] = (int)(rowbase0 + r);
        }
    }
    #pragma unroll
    for (int m = 1; m <= 32; m <<= 1) esum += __shfl_xor(esum, m);
    if (lane == 0) red[wv] = esum;
    __syncthreads();
    if (tid == 0) atomicAdd(&ws[WS_ESUM + view], red[0] + red[1] + red[2] + red[3]);
}

// ============================ kernel B2: exact-fp32 fixup (worklist) ============================
__global__ __launch_bounds__(256) void fixup_kernel(
    const float* __restrict__ h, const float* __restrict__ Wwin,
    const float* __restrict__ alpha, const float* __restrict__ ws,
    const int* __restrict__ wsi, float* __restrict__ out)
{
    __shared__ float hrow[DA];
    __shared__ float red[8];
    const int tid  = threadIdx.x;
    const int lane = tid & 63;
    const int wv   = tid >> 6;
    const int cnt  = wsi[WS_CNT];
    const int m    = cnt < CAP ? cnt : CAP;

    for (int i = blockIdx.x; i < m; i += gridDim.x) {
        const int row = wsi[WS_LIST + i];
        hrow[tid] = h[(size_t)row * DA + tid];
        __syncthreads();
        const float4* wr = (const float4*)(Wwin + (size_t)tid * DA);
        const float4* h4 = (const float4*)hrow;
        float z0 = 0.f, z1 = 0.f, z2 = 0.f, z3 = 0.f;
        #pragma unroll 4
        for (int j = 0; j < 64; j += 4) {
            float4 a, b;
            a = wr[j];   b = h4[j];   z0 += a.x*b.x + a.y*b.y + a.z*b.z + a.w*b.w;
            a = wr[j+1]; b = h4[j+1]; z1 += a.x*b.x + a.y*b.y + a.z*b.z + a.w*b.w;
            a = wr[j+2]; b = h4[j+2]; z2 += a.x*b.x + a.y*b.y + a.z*b.z + a.w*b.w;
            a = wr[j+3]; b = h4[j+3]; z3 += a.x*b.x + a.y*b.y + a.z*b.z + a.w*b.w;
        }
        float zz  = (z0 + z1) + (z2 + z3);
        float nrm = zz * zz;
        float num = hrow[tid] * ws[WS_W + tid];
        #pragma unroll
        for (int s = 1; s <= 32; s <<= 1) { nrm += __shfl_xor(nrm, s); num += __shfl_xor(num, s); }
        if (lane == 0) { red[wv] = nrm; red[4 + wv] = num; }
        __syncthreads();
        if (tid == 0) {
            float nn = red[0] + red[1] + red[2] + red[3];
            float uu = red[4] + red[5] + red[6] + red[7];
            out[OUT_E + row] = uu / fmaxf(sqrtf(nn), 1e-12f);
        }
        __syncthreads();
    }

    // overflow fallback (cnt > CAP never happens in practice; kept for strict correctness)
    if (cnt > CAP) {
        for (long i = blockIdx.x; i < (long)V * T; i += gridDim.x) {
            float r = -0.5f * alpha[i >> 13];
            if (fabsf(out[OUT_E + i] - r) >= MARGIN) continue;
            hrow[tid] = h[(size_t)i * DA + tid];
            __syncthreads();
            const float4* wr = (const float4*)(Wwin + (size_t)tid * DA);
            const float4* h4 = (const float4*)hrow;
            float z0 = 0.f, z1 = 0.f, z2 = 0.f, z3 = 0.f;
            for (int j = 0; j < 64; j += 4) {
                float4 a, b;
                a = wr[j];   b = h4[j];   z0 += a.x*b.x + a.y*b.y + a.z*b.z + a.w*b.w;
                a = wr[j+1]; b = h4[j+1]; z1 += a.x*b.x + a.y*b.y + a.z*b.z + a.w*b.w;
                a = wr[j+2]; b = h4[j+2]; z2 += a.x*b.x + a.y*b.y + a.z*b.z + a.w*b.w;
                a = wr[j+3]; b = h4[j+3]; z3 += a.x*b.x + a.y*b.y + a.z*b.z + a.w*b.w;
            }
            float zz  = (z0 + z1) + (z2 + z3);
            float nrm = zz * zz;
            float num = hrow[tid] * ws[WS_W + tid];
            for (int s = 1; s <= 32; s <<= 1) { nrm += __shfl_xor(nrm, s); num += __shfl_xor(num, s); }
            if (lane == 0) { red[wv] = nrm; red[4 + wv] = num; }
            __syncthreads();
            if (tid == 0) {
                float nn = red[0] + red[1] + red[2] + red[3];
                float uu = red[4] + red[5] + red[6] + red[7];
                out[OUT_E + i] = uu / fmaxf(sqrtf(nn), 1e-12f);
            }
            __syncthreads();
        }
    }
}

// ============================ kernel C: starts/ends + view finalize ============================
__global__ __launch_bounds__(256) void intervals_kernel(
    const float* __restrict__ alpha, const float* __restrict__ ws,
    float* __restrict__ out)
{
    int idx = blockIdx.x * 256 + threadIdx.x;
    int v = idx >> 13;
    int t = idx & (T - 1);
    const float* e = out + OUT_E;
    float r = -0.5f * alpha[v];
    bool Ii = (e[idx] >= r);
    bool Ip = (t > 0)     && (e[idx - 1] >= r);
    bool In = (t < T - 1) && (e[idx + 1] >= r);
    out[OUT_STARTS + idx] = (Ii && !Ip) ? 1.0f : 0.0f;
    out[OUT_ENDS   + idx] = (Ii && !In) ? 1.0f : 0.0f;

    // absorbed finalize: one wave of block 0 handles the 64 views
    if (blockIdx.x == 0 && threadIdx.x < 64) {
        int vv = threadIdx.x;
        float E = ws[WS_ESUM + vv] * (1.0f / 8192.0f);
        out[OUT_EVIEW + vv] = E;
        float rr = -0.5f * alpha[vv];
        bool Iv = (E >= rr);
        out[OUT_IVIEW + vv] = Iv ? 1.0f : 0.0f;
        unsigned long long bal = __ballot(Iv);
        if (vv == 0) {
            float p = out[OUT_PDET];
            out[OUT_FLAG] = ((p >= 0.5f) && (bal == 0ULL)) ? 1.0f : 0.0f;
        }
    }
}

// ============================ launcher ============================
extern "C" void kernel_launch(void* const* d_in, const int* in_sizes, int n_in,
                              void* d_out, int out_size, void* d_ws, size_t ws_size,
                              hipStream_t stream)
{
    const float* h      = (const float*)d_in[0];
    const float* alpha  = (const float*)d_in[1];
    const float* pi     = (const float*)d_in[2];
    const float* US     = (const float*)d_in[3];
    const float* Ws_w   = (const float*)d_in[6];
    const float* Ws_b   = (const float*)d_in[7];
    const float* det_w  = (const float*)d_in[8];
    const float* det_b  = (const float*)d_in[9];
    const float* cls_w  = (const float*)d_in[10];
    const float* cls_b  = (const float*)d_in[11];
    const float* Wwin   = (const float*)d_in[12];
    const float* tau_c0 = (const float*)d_in[13];
    const float* lamU   = (const float*)d_in[14];
    const float* lamC   = (const float*)d_in[15];
    const float* lamP   = (const float*)d_in[16];
    const float* lamPi  = (const float*)d_in[17];
    const float* nu     = (const float*)d_in[18];
    const float* risk   = (const float*)d_in[19];
    float* out = (float*)d_out;
    float* ws  = (float*)d_ws;
    int*   wsi = (int*)d_ws;

    head_kernel<<<1, 256, 0, stream>>>(alpha, pi, US, Ws_w, Ws_b, det_w, det_b,
                                       cls_w, cls_b, tau_c0, lamU, lamC,
                                       lamP, lamPi, nu, risk, out, ws, wsi);
    // escore only needs zsn (from head); start the long pole immediately.
    escore_kernel<<<512, 256, 0, stream>>>(h, Wwin, alpha, ws, wsi, out);
    // wvec result (WS_W) is only needed by fixup.
    wvec_kernel<<<16, 256, 0, stream>>>(Wwin, ws);
    fixup_kernel<<<512, 256, 0, stream>>>(h, Wwin, alpha, ws, wsi, out);
    intervals_kernel<<<(V * T) / 256, 256, 0, stream>>>(alpha, ws, out);
}